// Round 6
// baseline (474.892 us; speedup 1.0000x reference)
//
#include <hip/hip_runtime.h>

typedef _Float16 f16;
typedef _Float16 f16x8 __attribute__((ext_vector_type(8)));
typedef float    f32x4 __attribute__((ext_vector_type(4)));

// ---------------- converts ----------------

__global__ void cvt_x(const float* __restrict__ x, f16* __restrict__ xh) {
    int i = blockIdx.x * blockDim.x + threadIdx.x;   // one per 8 elems
    const f32x4* xv = (const f32x4*)x;
    f32x4 a = xv[2 * i], b = xv[2 * i + 1];
    f16x8 h;
    h[0] = (f16)a[0]; h[1] = (f16)a[1]; h[2] = (f16)a[2]; h[3] = (f16)a[3];
    h[4] = (f16)b[0]; h[5] = (f16)b[1]; h[6] = (f16)b[2]; h[7] = (f16)b[3];
    ((f16x8*)xh)[i] = h;
}

// Wt packed rows: [0,1024)=Wq^T, [1024,2048)=Wk^T, [2048,3072)=Wv^T  (N-major [n][k])
__global__ void cvt_transpose_w(const float* __restrict__ Wq, const float* __restrict__ Wk,
                                const float* __restrict__ Wv, f16* __restrict__ Wt) {
    const float* W = blockIdx.z == 0 ? Wq : (blockIdx.z == 1 ? Wk : Wv);
    __shared__ float tile[32][33];
    int tx = threadIdx.x, ty = threadIdx.y;          // 32 x 8
    int n0 = blockIdx.x * 32, k0 = blockIdx.y * 32;
#pragma unroll
    for (int r = 0; r < 4; ++r)
        tile[ty + r * 8][tx] = W[(size_t)(k0 + ty + r * 8) * 1024 + n0 + tx];
    __syncthreads();
    f16* o = Wt + (size_t)blockIdx.z * 1024 * 1024;
#pragma unroll
    for (int r = 0; r < 4; ++r)
        o[(size_t)(n0 + ty + r * 8) * 1024 + k0 + tx] = (f16)tile[tx][ty + r * 8];
}

// -------- 128x128 MFMA GEMM — LDS-FREE, register double-buffered --------
// C[m][n] = scale * sum_k A[m][k] * B[n][k]      (B is N-major / "B^T")
// No __syncthreads, no LDS: each wave owns a 64x64 tile and loads its MFMA
// fragments directly from global (frag layout row=lane&15, k=quad*8+j is a
// clean dwordx4 pattern). Twin waves re-read the same 64B lines -> L1 hits.
// MODE 0: fused projection. grid (16,96). bm<64: C_qk = xh @ [Wq|Wk]^T rows.
//         bm>=64: Vt[b] = Wv^T rows (M) x xh[b] rows (N). All f16 out.
// MODE 1: P' = exp(scale*acc), causal zero, f16 out, row-sums -> lsum (atomic).
//         grid (136,1,4) compact lower-triangle.
// MODE 2: f32 out * (1/lsum[row]); ktiles clamped to 4*(bm+1); bm reversed.
// ktiles must be EVEN (true for all three uses).
template <int MODE>
__global__ __launch_bounds__(256, 3)
void gemm128(const f16* __restrict__ A, int lda, long aStride,
             const f16* __restrict__ B, int ldb, long bStride,
             void* __restrict__ Cout, int ldc, long cStride,
             int ktiles, float scale, float* __restrict__ lsum,
             const f16* __restrict__ A2, const f16* __restrict__ B2,
             void* __restrict__ C2) {
    int bm, bn, bz = blockIdx.z;
    int m0, n0;
    const f16 *Ab, *Bb;
    char* Cb;

    if (MODE == 0) {
        bn = blockIdx.x; bm = blockIdx.y;
        n0 = bn * 128;
        if (bm < 64) {               // QK projection: A=xh, B=Wt(q|k), C=qk
            m0 = bm * 128;
            Ab = A; Bb = B; Cb = (char*)Cout;
        } else {                     // V^T: A=Wv^T, B=xh[b], C=Vt[b]
            int t = bm - 64;
            int bb = t >> 3;
            m0 = (t & 7) * 128;
            Ab = A2;
            Bb = B2 + (long)bb * 2048 * 1024;
            Cb = (char*)C2 + (long)bb * 1024 * 2048 * sizeof(f16);
        }
    } else if (MODE == 1) {
        int i = blockIdx.x;          // compact lower triangle, 136 entries
        float ff = sqrtf(8.f * (float)i + 1.f);
        bm = (int)((ff - 1.f) * 0.5f);
        while ((bm + 1) * (bm + 2) / 2 <= i) ++bm;
        while (bm * (bm + 1) / 2 > i) --bm;
        bn = i - bm * (bm + 1) / 2;
        m0 = bm * 128; n0 = bn * 128;
        Ab = A + (long)bz * aStride;
        Bb = B + (long)bz * bStride;
        Cb = (char*)Cout + (long)bz * cStride * sizeof(f16);
    } else {
        bn = blockIdx.x; bm = gridDim.y - 1 - blockIdx.y;   // long blocks first
        int lim = 4 * (bm + 1); if (lim < ktiles) ktiles = lim;
        m0 = bm * 128; n0 = bn * 128;
        Ab = A + (long)bz * aStride;
        Bb = B + (long)bz * bStride;
        Cb = (char*)Cout + (long)bz * cStride * sizeof(float);
    }

    const int tid = threadIdx.x;
    const int wave = tid >> 6, lane = tid & 63;
    const int q = lane >> 4, rr = lane & 15;
    const int wm = (wave >> 1) * 64, wn = (wave & 1) * 64;

    // per-lane fragment base pointers (16B aligned)
    const f16* pA = Ab + (long)(m0 + wm + rr) * lda + q * 8;
    const f16* pB = Bb + (long)(n0 + wn + rr) * ldb + q * 8;

    f16x8 af[2][4], bf[2][4];
    f32x4 acc[4][4] = {};

#define LOADF(kt, buf)                                                        \
    {                                                                         \
        const int k0_ = (kt) * 32;                                            \
        _Pragma("unroll")                                                     \
        for (int i_ = 0; i_ < 4; ++i_) {                                      \
            af[buf][i_] = *(const f16x8*)(pA + (long)i_ * 16 * lda + k0_);    \
            bf[buf][i_] = *(const f16x8*)(pB + (long)i_ * 16 * ldb + k0_);    \
        }                                                                     \
    }

#define MFMA_STEP(buf)                                                        \
    {                                                                         \
        _Pragma("unroll")                                                     \
        for (int i_ = 0; i_ < 4; ++i_)                                        \
            _Pragma("unroll")                                                 \
            for (int j_ = 0; j_ < 4; ++j_)                                    \
                acc[i_][j_] = __builtin_amdgcn_mfma_f32_16x16x32_f16(         \
                    af[buf][i_], bf[buf][j_], acc[i_][j_], 0, 0, 0);          \
    }

    LOADF(0, 0);
    LOADF(1, 1);
    for (int kt = 0; kt < ktiles; kt += 2) {
        MFMA_STEP(0);                            // consume kt
        if (kt + 2 < ktiles) LOADF(kt + 2, 0);   // refill buf0 (flies over step 1)
        MFMA_STEP(1);                            // consume kt+1
        if (kt + 3 < ktiles) LOADF(kt + 3, 1);   // refill buf1 (flies over step 0)
    }
#undef LOADF
#undef MFMA_STEP

    // epilogue: C/D layout col=lane&15, row=(lane>>4)*4+reg
#pragma unroll
    for (int i = 0; i < 4; ++i) {
#pragma unroll
        for (int r2 = 0; r2 < 4; ++r2) {
            const int row = wm + i * 16 + q * 4 + r2;       // local 0..127
            float psum = 0.f;
            float inv = 1.f;
            if (MODE == 2) inv = 1.0f / lsum[bz * 2048 + m0 + row];
#pragma unroll
            for (int j = 0; j < 4; ++j) {
                const int col = wn + j * 16 + rr;           // local 0..127
                float v = acc[i][j][r2] * scale;
                long idx = (long)(m0 + row) * ldc + n0 + col;
                if (MODE == 1) {
                    v = __expf(v);
                    if (n0 + col > m0 + row) v = 0.f;
                    psum += v;
                    ((f16*)Cb)[idx] = (f16)v;
                } else if (MODE == 0) {
                    ((f16*)Cb)[idx] = (f16)v;
                } else {
                    ((float*)Cb)[idx] = v * inv;
                }
            }
            if (MODE == 1) {
                psum += __shfl_xor(psum, 1, 64);
                psum += __shfl_xor(psum, 2, 64);
                psum += __shfl_xor(psum, 4, 64);
                psum += __shfl_xor(psum, 8, 64);
                if (rr == 0) atomicAdd(&lsum[bz * 2048 + m0 + row], psum);
            }
        }
    }
}

// ---------------- launch ----------------
extern "C" void kernel_launch(void* const* d_in, const int* in_sizes, int n_in,
                              void* d_out, int out_size, void* d_ws, size_t ws_size,
                              hipStream_t stream) {
    (void)in_sizes; (void)n_in; (void)out_size; (void)ws_size;
    const float* x  = (const float*)d_in[0];
    const float* Wk = (const float*)d_in[1];
    const float* Wq = (const float*)d_in[2];
    const float* Wv = (const float*)d_in[3];
    float* out = (float*)d_out;

    const long MB = 1l << 20;
    char* ws = (char*)d_ws;
    f16*   qk   = (f16*)(ws);             // 32 MB: [4*2048][2048]  (Q cols 0-1023 | K cols 1024-2047)
    f16*   Vt   = (f16*)(ws + 32 * MB);   // 16 MB: [4][1024][2048] (V^T)
    f16*   P    = (f16*)(ws + 48 * MB);   // 32 MB: [4][2048][2048] unnormalized exp-scores
    float* lsum = (float*)(ws + 80 * MB); // 32 KB: [4*2048] row sums
    f16*   xh   = (f16*)(ws + 81 * MB);   // 16 MB
    f16*   Wt   = (f16*)(ws + 97 * MB);   //  6 MB

    cvt_x<<<4096, 256, 0, stream>>>(x, xh);
    cvt_transpose_w<<<dim3(32, 32, 3), dim3(32, 8), 0, stream>>>(Wq, Wk, Wv, Wt);
    hipMemsetAsync(lsum, 0, 4 * 2048 * sizeof(float), stream);

    // Fused projection: bm<64 -> qk[8192,2048] = xh @ [Wq|Wk]^T ; bm>=64 -> Vt[b][h][t]
    gemm128<0><<<dim3(16, 96, 1), 256, 0, stream>>>(xh, 1024, 0, Wt, 1024, 0,
                                                    qk, 2048, 0, 32, 1.0f, nullptr,
                                                    Wt + 2l * 1024 * 1024, xh, Vt);
    // P' = exp(Q K^T / 32), causal-zeroed, + row sums (compact lower-triangle grid)
    gemm128<1><<<dim3(136, 1, 4), 256, 0, stream>>>(qk, 2048, 2048l * 2048,
                                                    qk + 1024, 2048, 2048l * 2048,
                                                    P, 2048, 2048l * 2048, 32, 0.03125f, lsum,
                                                    nullptr, nullptr, nullptr);
    // O = (P' V) / lsum  (k-range clamped per row-block, long blocks dispatched first)
    gemm128<2><<<dim3(8, 16, 4), 256, 0, stream>>>(P, 2048, 2048l * 2048,
                                                   Vt, 2048, 1024l * 2048,
                                                   out, 1024, 2048l * 1024, 64, 1.0f, lsum,
                                                   nullptr, nullptr, nullptr);
}

// Round 7
// 243.673 us; speedup vs baseline: 1.9489x; 1.9489x over previous
//
#include <hip/hip_runtime.h>

typedef _Float16 f16;
typedef _Float16 f16x8 __attribute__((ext_vector_type(8)));
typedef float    f32x4 __attribute__((ext_vector_type(4)));

#define AS3 __attribute__((address_space(3)))
#define AS1 __attribute__((address_space(1)))

// async global->LDS, 16B per lane. LDS dest = wave-uniform base + lane*16.
static __device__ __forceinline__ void gld_lds16(const f16* g, f16* l) {
    __builtin_amdgcn_global_load_lds((const AS1 void*)g, (AS3 void*)l, 16, 0, 0);
}

// ---------------- converts ----------------

__global__ void cvt_x(const float* __restrict__ x, f16* __restrict__ xh) {
    int i = blockIdx.x * blockDim.x + threadIdx.x;   // one per 8 elems
    const f32x4* xv = (const f32x4*)x;
    f32x4 a = xv[2 * i], b = xv[2 * i + 1];
    f16x8 h;
    h[0] = (f16)a[0]; h[1] = (f16)a[1]; h[2] = (f16)a[2]; h[3] = (f16)a[3];
    h[4] = (f16)b[0]; h[5] = (f16)b[1]; h[6] = (f16)b[2]; h[7] = (f16)b[3];
    ((f16x8*)xh)[i] = h;
}

// Wt packed rows: [0,1024)=Wq^T, [1024,2048)=Wk^T, [2048,3072)=Wv^T  (N-major [n][k])
__global__ void cvt_transpose_w(const float* __restrict__ Wq, const float* __restrict__ Wk,
                                const float* __restrict__ Wv, f16* __restrict__ Wt) {
    const float* W = blockIdx.z == 0 ? Wq : (blockIdx.z == 1 ? Wk : Wv);
    __shared__ float tile[32][33];
    int tx = threadIdx.x, ty = threadIdx.y;          // 32 x 8
    int n0 = blockIdx.x * 32, k0 = blockIdx.y * 32;
#pragma unroll
    for (int r = 0; r < 4; ++r)
        tile[ty + r * 8][tx] = W[(size_t)(k0 + ty + r * 8) * 1024 + n0 + tx];
    __syncthreads();
    f16* o = Wt + (size_t)blockIdx.z * 1024 * 1024;
#pragma unroll
    for (int r = 0; r < 4; ++r)
        o[(size_t)(n0 + ty + r * 8) * 1024 + k0 + tx] = (f16)tile[tx][ty + r * 8];
}

// -------- 128x128 MFMA GEMM, BK=32 dbuf LDS, XOR-SWIZZLED k-chunks --------
// C[m][n] = scale * sum_k A[m][k] * B[n][k]      (B is N-major / "B^T")
// LDS layout: tile element (row, kc) lives at slot (kc + (row>>2)) & 3 of
// row's 4 x 16B chunks. Fragment read (row, q) -> bank-quad (2*row + ...)%8
// is uniformly 2 lanes/quad = conflict-free (m136: 2-way is free).
// Staging inverse is lane-constant: kc = ((tid&3) - (lane>>4)) & 3.
// MODE 0: fused projection. grid (16,96). bm<64: C_qk = xh @ [Wq|Wk]^T rows.
//         bm>=64: Vt[b] = Wv^T rows (M) x xh[b] rows (N). All f16 out.
// MODE 1: P' = exp(scale*acc), causal zero, f16 out, row-sums -> lsum (atomic).
//         grid (136,1,4) compact lower-triangle.
// MODE 2: f32 out * (1/lsum[row]); ktiles clamped to 4*(bm+1); bm reversed.
template <int MODE>
__global__ __launch_bounds__(256, 4)
void gemm128(const f16* __restrict__ A, int lda, long aStride,
             const f16* __restrict__ B, int ldb, long bStride,
             void* __restrict__ Cout, int ldc, long cStride,
             int ktiles, float scale, float* __restrict__ lsum,
             const f16* __restrict__ A2, const f16* __restrict__ B2,
             void* __restrict__ C2) {
    int bm, bn, bz = blockIdx.z;
    int m0, n0;
    const f16 *Ab, *Bb;
    char* Cb;

    if (MODE == 0) {
        bn = blockIdx.x; bm = blockIdx.y;
        n0 = bn * 128;
        if (bm < 64) {               // QK projection: A=xh, B=Wt(q|k), C=qk
            m0 = bm * 128;
            Ab = A; Bb = B; Cb = (char*)Cout;
        } else {                     // V^T: A=Wv^T, B=xh[b], C=Vt[b]
            int t = bm - 64;
            int bb = t >> 3;
            m0 = (t & 7) * 128;
            Ab = A2;
            Bb = B2 + (long)bb * 2048 * 1024;
            Cb = (char*)C2 + (long)bb * 1024 * 2048 * sizeof(f16);
        }
    } else if (MODE == 1) {
        int i = blockIdx.x;          // compact lower triangle, 136 entries
        float ff = sqrtf(8.f * (float)i + 1.f);
        bm = (int)((ff - 1.f) * 0.5f);
        while ((bm + 1) * (bm + 2) / 2 <= i) ++bm;
        while (bm * (bm + 1) / 2 > i) --bm;
        bn = i - bm * (bm + 1) / 2;
        m0 = bm * 128; n0 = bn * 128;
        Ab = A + (long)bz * aStride;
        Bb = B + (long)bz * bStride;
        Cb = (char*)Cout + (long)bz * cStride * sizeof(f16);
    } else {
        bn = blockIdx.x; bm = gridDim.y - 1 - blockIdx.y;   // long blocks first
        int lim = 4 * (bm + 1); if (lim < ktiles) ktiles = lim;
        m0 = bm * 128; n0 = bn * 128;
        Ab = A + (long)bz * aStride;
        Bb = B + (long)bz * bStride;
        Cb = (char*)Cout + (long)bz * cStride * sizeof(float);
    }

    __shared__ f16 lds[2 * 8192];    // [buf][A:4096 f16 | B:4096 f16] = 32 KiB

    const int tid = threadIdx.x;
    const int wave = tid >> 6, lane = tid & 63;
    const int q = lane >> 4, rr = lane & 15;
    const int wm = (wave >> 1) * 64, wn = (wave & 1) * 64;

    // staging: LDS slot s = wave*64 + it*256 + lane holds tile row s>>2,
    // slot_kc = lane&3 -> global k-chunk kc = (slot_kc - (row>>2)) & 3,
    // and (row>>2)&3 reduces to (lane>>4) -> lane-constant swizzled column.
    const int kcs = (((tid & 3) - (lane >> 4)) & 3) * 8;   // f16 col within BK=32
    const f16* pA = Ab + (long)(m0 + (tid >> 2)) * lda + kcs;
    const f16* pB = Bb + (long)(n0 + (tid >> 2)) * ldb + kcs;

    auto stage = [&](int kt, int buf) {
        const int k0 = kt * 32;
        f16* lA = lds + buf * 8192 + wave * 512;           // + lane*16B by HW
        f16* lB = lds + buf * 8192 + 4096 + wave * 512;
#pragma unroll
        for (int it = 0; it < 2; ++it) {
            gld_lds16(pA + (long)it * 64 * lda + k0, lA + it * 2048);
            gld_lds16(pB + (long)it * 64 * ldb + k0, lB + it * 2048);
        }
    };

    // fragment read: (row, q) lives at slot (q + (row>>2)) & 3; row = wm+i*16+rr
    // -> slot = (q + (rr>>2)) & 3 (i*16, wm drop out mod 4)
    const int slotf = ((q + (rr >> 2)) & 3) * 8;           // f16 col within row

    f32x4 acc[4][4] = {};

    stage(0, 0);
    __syncthreads();                 // drains vmcnt -> buf0 ready

    for (int kt = 0; kt < ktiles; ++kt) {
        const int cur = kt & 1;
        if (kt + 1 < ktiles) stage(kt + 1, 1 - cur);   // issue BEFORE compute
        const f16* bufA = lds + cur * 8192;
        const f16* bufB = bufA + 4096;
        f16x8 af[4], bf[4];
#pragma unroll
        for (int i = 0; i < 4; ++i)
            af[i] = *(const f16x8*)&bufA[(wm + i * 16 + rr) * 32 + slotf];
#pragma unroll
        for (int j = 0; j < 4; ++j)
            bf[j] = *(const f16x8*)&bufB[(wn + j * 16 + rr) * 32 + slotf];
#pragma unroll
        for (int i = 0; i < 4; ++i)
#pragma unroll
            for (int j = 0; j < 4; ++j)
                acc[i][j] = __builtin_amdgcn_mfma_f32_16x16x32_f16(af[i], bf[j], acc[i][j], 0, 0, 0);
        __syncthreads();             // prefetch landed (flew during MFMA phase) + handoff
    }

    // epilogue: C/D layout col=lane&15, row=(lane>>4)*4+reg
#pragma unroll
    for (int i = 0; i < 4; ++i) {
#pragma unroll
        for (int r2 = 0; r2 < 4; ++r2) {
            const int row = wm + i * 16 + q * 4 + r2;       // local 0..127
            float psum = 0.f;
            float inv = 1.f;
            if (MODE == 2) inv = 1.0f / lsum[bz * 2048 + m0 + row];
#pragma unroll
            for (int j = 0; j < 4; ++j) {
                const int col = wn + j * 16 + rr;           // local 0..127
                float v = acc[i][j][r2] * scale;
                long idx = (long)(m0 + row) * ldc + n0 + col;
                if (MODE == 1) {
                    v = __expf(v);
                    if (n0 + col > m0 + row) v = 0.f;
                    psum += v;
                    ((f16*)Cb)[idx] = (f16)v;
                } else if (MODE == 0) {
                    ((f16*)Cb)[idx] = (f16)v;
                } else {
                    ((float*)Cb)[idx] = v * inv;
                }
            }
            if (MODE == 1) {
                psum += __shfl_xor(psum, 1, 64);
                psum += __shfl_xor(psum, 2, 64);
                psum += __shfl_xor(psum, 4, 64);
                psum += __shfl_xor(psum, 8, 64);
                if (rr == 0) atomicAdd(&lsum[bz * 2048 + m0 + row], psum);
            }
        }
    }
}

// ---------------- launch ----------------
extern "C" void kernel_launch(void* const* d_in, const int* in_sizes, int n_in,
                              void* d_out, int out_size, void* d_ws, size_t ws_size,
                              hipStream_t stream) {
    (void)in_sizes; (void)n_in; (void)out_size; (void)ws_size;
    const float* x  = (const float*)d_in[0];
    const float* Wk = (const float*)d_in[1];
    const float* Wq = (const float*)d_in[2];
    const float* Wv = (const float*)d_in[3];
    float* out = (float*)d_out;

    const long MB = 1l << 20;
    char* ws = (char*)d_ws;
    f16*   qk   = (f16*)(ws);             // 32 MB: [4*2048][2048]  (Q cols 0-1023 | K cols 1024-2047)
    f16*   Vt   = (f16*)(ws + 32 * MB);   // 16 MB: [4][1024][2048] (V^T)
    f16*   P    = (f16*)(ws + 48 * MB);   // 32 MB: [4][2048][2048] unnormalized exp-scores
    float* lsum = (float*)(ws + 80 * MB); // 32 KB: [4*2048] row sums
    f16*   xh   = (f16*)(ws + 81 * MB);   // 16 MB
    f16*   Wt   = (f16*)(ws + 97 * MB);   //  6 MB

    cvt_x<<<4096, 256, 0, stream>>>(x, xh);
    cvt_transpose_w<<<dim3(32, 32, 3), dim3(32, 8), 0, stream>>>(Wq, Wk, Wv, Wt);
    hipMemsetAsync(lsum, 0, 4 * 2048 * sizeof(float), stream);

    // Fused projection: bm<64 -> qk[8192,2048] = xh @ [Wq|Wk]^T ; bm>=64 -> Vt[b][h][t]
    gemm128<0><<<dim3(16, 96, 1), 256, 0, stream>>>(xh, 1024, 0, Wt, 1024, 0,
                                                    qk, 2048, 0, 32, 1.0f, nullptr,
                                                    Wt + 2l * 1024 * 1024, xh, Vt);
    // P' = exp(Q K^T / 32), causal-zeroed, + row sums (compact lower-triangle grid)
    gemm128<1><<<dim3(136, 1, 4), 256, 0, stream>>>(qk, 2048, 2048l * 2048,
                                                    qk + 1024, 2048, 2048l * 2048,
                                                    P, 2048, 2048l * 2048, 32, 0.03125f, lsum,
                                                    nullptr, nullptr, nullptr);
    // O = (P' V) / lsum  (k-range clamped per row-block, long blocks dispatched first)
    gemm128<2><<<dim3(8, 16, 4), 256, 0, stream>>>(P, 2048, 2048l * 2048,
                                                   Vt, 2048, 1024l * 2048,
                                                   out, 1024, 2048l * 1024, 64, 1.0f, lsum,
                                                   nullptr, nullptr, nullptr);
}